// Round 21
// baseline (220.401 us; speedup 1.0000x reference)
//
#include <hip/hip_runtime.h>

#define NN 20000
#define MM 5000
#define EE 320000
#define FD 128          // HEADS*OUT
#define KD 5000         // GEMM K == MM
#define K2 5120         // padded K (80 * 64)
#define NEG 0.2f
#define BK 64           // GEMM K-step (256B per H row per tile)
#define BUFB 49152      // one LDS buffer: A-f32(32KB) + B-bf16(16KB)
#define BOFF 32768      // B region offset inside a buffer
#define NKT 80          // total K-tiles (5120/64)
#define SPLITK 4
#define KTPS 20         // K-tiles per split (exact: 4*20=80)

typedef __attribute__((ext_vector_type(4))) float f32x4;
typedef __attribute__((ext_vector_type(8))) short short8;

__device__ __forceinline__ unsigned int f2bf(float x){
  unsigned int u = __float_as_uint(x);
  return (u + 0x7fffu + ((u >> 16) & 1u)) >> 16;   // RNE
}
__device__ __forceinline__ unsigned int cvtpk(float lo, float hi){
  unsigned int r;
  asm volatile("v_cvt_pk_bf16_f32 %0, %1, %2" : "=v"(r) : "v"(lo), "v"(hi));
  return r;
}
__device__ __forceinline__ void dma16(const void* g, void* l){
  __builtin_amdgcn_global_load_lds(
      (const __attribute__((address_space(1))) void*)g,
      (__attribute__((address_space(3))) void*)l, 16, 0, 0);
}

// ---- prep (fused k_el + k_feat16 + k_count): feat stream -> el + bf16 table;
// ---- first EE threads also histogram dst --------------------------------
__global__ __launch_bounds__(256) void k_prep(const float* __restrict__ feat,
                                              const float* __restrict__ attn_l,
                                              const int* __restrict__ dst,
                                              int* __restrict__ counts,
                                              float* __restrict__ el,
                                              unsigned int* __restrict__ fb){
  int t = threadIdx.x;
  int g = blockIdx.x*256 + t;
  if (g < EE) atomicAdd(&counts[dst[g]], 1);
  int node = blockIdx.x*4 + (t>>6);
  int l = t & 63;
  float2 f = ((const float2*)feat)[(size_t)node*64 + l];
  fb[(size_t)node*64 + l] = cvtpk(f.x, f.y);
  float p = f.x*attn_l[2*l] + f.y*attn_l[2*l+1];
  p += __shfl_xor(p,1); p += __shfl_xor(p,2); p += __shfl_xor(p,4); p += __shfl_xor(p,8);
  if ((l&15)==0) el[node*4 + (l>>4)] = p;
}

// ---------------- CSR scan --------------------------------------------------
__global__ __launch_bounds__(256) void k_scan(const int* __restrict__ counts,
                                              int* __restrict__ offsets){
  __shared__ int sc[256];
  int t = threadIdx.x;
  int loc[20];
  int sum = 0;
  #pragma unroll
  for (int j=0;j<20;j++){
    int idx = t*20 + j;
    int v = (idx < MM) ? counts[idx] : 0;
    loc[j] = sum; sum += v;
  }
  sc[t] = sum; __syncthreads();
  for (int s=1; s<256; s<<=1){
    int v = 0;
    if (t >= s) v = sc[t-s];
    __syncthreads();
    if (t >= s) sc[t] += v;
    __syncthreads();
  }
  int base = sc[t] - sum;   // exclusive over thread blocks
  #pragma unroll
  for (int j=0;j<20;j++){
    int idx = t*20 + j;
    if (idx < MM) offsets[idx] = base + loc[j];
  }
  if (t == 250) offsets[MM] = base;   // = total E
}

// ---- edge logits + DIRECT dst-sorted scatter (fused k_edge + k_scatter) ----
__global__ __launch_bounds__(256) void k_edge_sc(const float* __restrict__ edge_feat,
                                                 const float* __restrict__ attn_m,
                                                 const float* __restrict__ el,
                                                 const int* __restrict__ src,
                                                 const int* __restrict__ dst,
                                                 const int* __restrict__ offsets,
                                                 int* __restrict__ cursor,
                                                 float4* __restrict__ e4_s,
                                                 int* __restrict__ src_s){
  __shared__ float am[128];
  int t = threadIdx.x;
  if (t < 128) am[t] = attn_m[t];
  __syncthreads();
  int e = blockIdx.x*16 + (t>>4);
  int c = t & 15;
  float2 f = ((const float2*)edge_feat)[(size_t)e*16 + c];
  float p0 = f.x*am[0*32+2*c] + f.y*am[0*32+2*c+1];
  float p1 = f.x*am[1*32+2*c] + f.y*am[1*32+2*c+1];
  float p2 = f.x*am[2*32+2*c] + f.y*am[2*32+2*c+1];
  float p3 = f.x*am[3*32+2*c] + f.y*am[3*32+2*c+1];
  #pragma unroll
  for (int s=1; s<16; s<<=1){
    p0 += __shfl_xor(p0,s); p1 += __shfl_xor(p1,s);
    p2 += __shfl_xor(p2,s); p3 += __shfl_xor(p3,s);
  }
  if (c==0){
    float4 ev = ((const float4*)el)[src[e]];
    float4 r;
    float v;
    v = ev.x + p0; r.x = v > 0.f ? v : NEG*v;
    v = ev.y + p1; r.y = v > 0.f ? v : NEG*v;
    v = ev.z + p2; r.z = v > 0.f ? v : NEG*v;
    v = ev.w + p3; r.w = v > 0.f ? v : NEG*v;
    int d = dst[e];
    int pos = offsets[d] + atomicAdd(&cursor[d], 1);
    e4_s[pos] = r;
    src_s[pos] = src[e];
  }
}

// ------- per-dst softmax + aggregate; writes aggT[c][k] (bf16, K2-padded) ---
// (R13-proven: sorted streams, bf16 feat gather, const-shift exp, unroll x2)
__global__ __launch_bounds__(256) void k_agg(const float4* __restrict__ e4_s,
                                             const int* __restrict__ src_s,
                                             const unsigned int* __restrict__ fb,
                                             const int* __restrict__ offsets,
                                             unsigned short* __restrict__ aggT){
  int m = blockIdx.x;
  int t = threadIdx.x;
  // zero the K-pad region (k in [5000, 5120)) once per call
  if (m < (K2 - KD) && t < FD) aggT[(size_t)t*K2 + KD + m] = 0;
  int beg = offsets[m], end = offsets[m+1];
  int cnt = end - beg;
  if (cnt == 0){
    if (t < FD) aggT[(size_t)t*K2 + m] = 0;  // bf16 zero
    return;
  }
  __shared__ float accs[4][FD];
  __shared__ float dens[4][4];
  int w = t>>6, l = t&63, h = l>>4;
  float accx=0.f, accy=0.f, den=0.f;
  int i = w;
  #pragma unroll 1
  for (; i+4 < cnt; i += 8){           // unroll x2: two gathers in flight
    float4 ev0 = e4_s[beg+i];
    float4 ev1 = e4_s[beg+i+4];
    int s0 = src_s[beg+i];
    int s1 = src_s[beg+i+4];
    unsigned int v0 = fb[(size_t)s0*64 + l];
    unsigned int v1 = fb[(size_t)s1*64 + l];
    float eh0 = (h==0)?ev0.x:((h==1)?ev0.y:((h==2)?ev0.z:ev0.w));
    float eh1 = (h==0)?ev1.x:((h==1)?ev1.y:((h==2)?ev1.z:ev1.w));
    float p0 = __expf(eh0 - 32.0f);
    float p1 = __expf(eh1 - 32.0f);
    accx += p0*__uint_as_float(v0<<16) + p1*__uint_as_float(v1<<16);
    accy += p0*__uint_as_float(v0&0xffff0000u) + p1*__uint_as_float(v1&0xffff0000u);
    den  += p0 + p1;
  }
  if (i < cnt){
    float4 ev = e4_s[beg+i];
    int s0 = src_s[beg+i];
    unsigned int v = fb[(size_t)s0*64 + l];
    float eh = (h==0)?ev.x:((h==1)?ev.y:((h==2)?ev.z:ev.w));
    float p = __expf(eh - 32.0f);
    accx += p*__uint_as_float(v<<16);
    accy += p*__uint_as_float(v&0xffff0000u);
    den  += p;
  }
  accs[w][2*l]   = accx;
  accs[w][2*l+1] = accy;
  if ((l&15)==0) dens[w][h] = den;
  __syncthreads();
  if (t < FD){
    float s = accs[0][t]+accs[1][t]+accs[2][t]+accs[3][t];
    float dn = dens[0][t>>5]+dens[1][t>>5]+dens[2][t>>5]+dens[3][t>>5];
    aggT[(size_t)t*K2 + m] = (unsigned short)f2bf(s/dn);
  }
}

// ------- GEMM: out[N][128] += H[N][ksplit] * agg[ksplit][128] ---------------
// BM=128 (HALVES B re-read traffic: per-CU vmem was the measured bottleneck
// at 10.2 B/cyc/CU), BN=128, BK=64. Proven R12 dma16 schedule shape:
// 512 thr / 8 waves (4Mx2N, wave tile 32x64), 2x48KB LDS buffers, counted
// vmcnt(6), 2 barriers/tile. A staged f32 (cvtpk at read), B bf16 direct.
// Swizzles: A 16-granule XOR rl, B 8-granule XOR (rl&7) -- <=2-way = free.
// Atomic split-K epilogue into memset-zeroed out (R17-proven).
__global__ __launch_bounds__(512, 2) void k_gemm(const float* __restrict__ H,
                                                 const unsigned short* __restrict__ aggT,
                                                 float* __restrict__ out){
  __shared__ char lds[2*BUFB];
  int t = threadIdx.x;
  int row0 = blockIdx.x * 128;
  int kt0 = blockIdx.y * KTPS;

  int w8 = t>>6, l = t&63;
  const size_t AMAX = (size_t)NN*KD - 4;

  // ---- fragment read addressing: wave (w8>>1) of 4 row-groups x (w8&1) of 2
  int wr = (w8>>1)*32, wc = (w8&1)*64;
  int rl = l&15, kg = l>>4;
  int arowA = (wr+rl)*256;             // A row byte offset (256B rows)
  int arowB = (wr+16+rl)*256;          // (wr+16+rl)&15 == rl
  int bx = rl & 7;                     // B granule xor (col&7 == rl&7)
  int bcol0 = BOFF + (wc+ 0+rl)*128;   // B col byte offsets (128B cols)
  int bcol1 = BOFF + (wc+16+rl)*128;
  int bcol2 = BOFF + (wc+32+rl)*128;
  int bcol3 = BOFF + (wc+48+rl)*128;

  f32x4 acc00={0,0,0,0}, acc01={0,0,0,0}, acc02={0,0,0,0}, acc03={0,0,0,0};
  f32x4 acc10={0,0,0,0}, acc11={0,0,0,0}, acc12={0,0,0,0}, acc13={0,0,0,0};

#define STAGE(KT, BUF)                                                        \
  { size_t kb_ = (size_t)(KT)*BK;                                             \
    _Pragma("unroll")                                                         \
    for (int j=0;j<4;j++){   /* A: 4 rows per instr, 256B runs */             \
      int r_ = row0 + w8*16 + j*4 + (l>>4);                                   \
      if (r_ > NN-1) r_ = NN-1;                                               \
      size_t s_ = (size_t)r_*KD + (size_t)((l&15) ^ (r_&15))*4 + kb_;         \
      if (s_ > AMAX) s_ = AMAX;                                               \
      dma16(H + s_, (BUF) + (w8*16 + j*4)*256);                               \
    }                                                                         \
    _Pragma("unroll")                                                         \
    for (int j=0;j<2;j++){   /* B: 8 cols per instr, 128B runs (L2-hit) */    \
      int c_ = w8*16 + j*8 + (l>>3);                                          \
      size_t s_ = (size_t)c_*K2 + (size_t)((l&7) ^ (c_&7))*8 + kb_;           \
      dma16(aggT + s_, (BUF) + BOFF + (w8*16 + j*8)*128);                     \
    }                                                                         \
  }

#define COMP_KK(R_, KK)                                                       \
  { int gA0 = (KK)*8 + kg*2;                                                  \
    int sA0 = ((gA0  ) ^ rl) << 4;                                            \
    int sA1 = ((gA0+1) ^ rl) << 4;                                            \
    f32x4 x0_ = *(const f32x4*)(R_ + arowA + sA0);                            \
    f32x4 x1_ = *(const f32x4*)(R_ + arowA + sA1);                            \
    f32x4 y0_ = *(const f32x4*)(R_ + arowB + sA0);                            \
    f32x4 y1_ = *(const f32x4*)(R_ + arowB + sA1);                            \
    int sB_ = (((KK)*4 + kg) ^ bx) << 4;                                      \
    short8 b0_ = *(const short8*)(R_ + bcol0 + sB_);                          \
    short8 b1_ = *(const short8*)(R_ + bcol1 + sB_);                          \
    short8 b2_ = *(const short8*)(R_ + bcol2 + sB_);                          \
    short8 b3_ = *(const short8*)(R_ + bcol3 + sB_);                          \
    uint4 ua_, ub_;                                                           \
    ua_.x = cvtpk(x0_[0],x0_[1]); ua_.y = cvtpk(x0_[2],x0_[3]);               \
    ua_.z = cvtpk(x1_[0],x1_[1]); ua_.w = cvtpk(x1_[2],x1_[3]);               \
    ub_.x = cvtpk(y0_[0],y0_[1]); ub_.y = cvtpk(y0_[2],y0_[3]);               \
    ub_.z = cvtpk(y1_[0],y1_[1]); ub_.w = cvtpk(y1_[2],y1_[3]);               \
    short8 a0_ = *(short8*)&ua_;                                              \
    short8 a1_ = *(short8*)&ub_;                                              \
    acc00 = __builtin_amdgcn_mfma_f32_16x16x32_bf16(a0_,b0_,acc00,0,0,0);     \
    acc01 = __builtin_amdgcn_mfma_f32_16x16x32_bf16(a0_,b1_,acc01,0,0,0);     \
    acc02 = __builtin_amdgcn_mfma_f32_16x16x32_bf16(a0_,b2_,acc02,0,0,0);     \
    acc03 = __builtin_amdgcn_mfma_f32_16x16x32_bf16(a0_,b3_,acc03,0,0,0);     \
    acc10 = __builtin_amdgcn_mfma_f32_16x16x32_bf16(a1_,b0_,acc10,0,0,0);     \
    acc11 = __builtin_amdgcn_mfma_f32_16x16x32_bf16(a1_,b1_,acc11,0,0,0);     \
    acc12 = __builtin_amdgcn_mfma_f32_16x16x32_bf16(a1_,b2_,acc12,0,0,0);     \
    acc13 = __builtin_amdgcn_mfma_f32_16x16x32_bf16(a1_,b3_,acc13,0,0,0);     \
  }

  STAGE(kt0,   lds)
  STAGE(kt0+1, lds + BUFB)

  int pr = 0;
  for (int tt = 0; tt < KTPS; ++tt){
    if (tt+1 < KTPS) { asm volatile("s_waitcnt vmcnt(6)" ::: "memory"); }
    else             { asm volatile("s_waitcnt vmcnt(0)" ::: "memory"); }
    __builtin_amdgcn_s_barrier();
    { const char* R_ = lds + pr*BUFB;
      COMP_KK(R_, 0)
      COMP_KK(R_, 1)
    }
    __builtin_amdgcn_s_barrier();
    __builtin_amdgcn_sched_barrier(0);
    if (tt+2 < KTPS) STAGE(kt0+tt+2, lds + pr*BUFB)
    pr ^= 1;
  }
#undef STAGE
#undef COMP_KK

  // epilogue: D row=(l>>4)*4+p, col=l&15 (m89-verified); split-K atomicAdd
#define STORE(ACC, FR, FN)                                                    \
  { _Pragma("unroll")                                                         \
    for (int q=0;q<4;q++){                                                    \
      int r = row0 + wr + (FR)*16 + kg*4 + q;                                 \
      if (r < NN) atomicAdd(&out[(size_t)r*FD + wc + (FN)*16 + rl], ACC[q]);  \
    } }
  STORE(acc00,0,0) STORE(acc01,0,1) STORE(acc02,0,2) STORE(acc03,0,3)
  STORE(acc10,1,0) STORE(acc11,1,1) STORE(acc12,1,2) STORE(acc13,1,3)
#undef STORE
}

extern "C" void kernel_launch(void* const* d_in, const int* in_sizes, int n_in,
                              void* d_out, int out_size, void* d_ws, size_t ws_size,
                              hipStream_t stream) {
  const float* feat      = (const float*)d_in[0];
  const float* edge_feat = (const float*)d_in[1];
  const float* H         = (const float*)d_in[2];
  const float* attn_l    = (const float*)d_in[3];
  const float* attn_m    = (const float*)d_in[4];
  const int*   src       = (const int*)d_in[5];
  const int*   dst       = (const int*)d_in[6];
  float* out = (float*)d_out;

  char* w = (char*)d_ws;
  // el ([0,320000)) and aggT ([0,1310720)) have disjoint lifetimes -> overlap
  float*          el       = (float*)(w + 0);                //  320000 B (dead after k_edge_sc)
  unsigned short* aggT     = (unsigned short*)(w + 0);       // 1310720 B (live from k_agg)
  int*            counts   = (int*)(w + 1310720);            //   20480 B
  int*            cursor   = (int*)(w + 1331200);            //   20480 B
  int*            offsets  = (int*)(w + 1351680);            //   20480 B
  int*            src_s    = (int*)(w + 1372160);            // 1280000 B
  float4*         e4_s     = (float4*)(w + 2652160);         // 5120000 B
  unsigned int*   fb       = (unsigned int*)(w + 7772160);   // 5120000 B (bf16 feat)
  // total ~12.9 MB

  hipMemsetAsync(counts, 0, 2*20480, stream);          // counts + cursor
  hipMemsetAsync(out, 0, (size_t)out_size*4, stream);  // split-K accumulator

  k_prep   <<<NN/4,   256, 0, stream>>>(feat, attn_l, dst, counts, el, fb);
  k_scan   <<<1,      256, 0, stream>>>(counts, offsets);
  k_edge_sc<<<EE/16,  256, 0, stream>>>(edge_feat, attn_m, el, src, dst,
                                        offsets, cursor, e4_s, src_s);
  k_agg    <<<MM,     256, 0, stream>>>(e4_s, src_s, fb, offsets, aggT);
  k_gemm   <<<dim3((NN+127)/128, SPLITK), 512, 0, stream>>>(H, aggT, out);
}

// Round 22
// 213.348 us; speedup vs baseline: 1.0331x; 1.0331x over previous
//
#include <hip/hip_runtime.h>

#define NN 20000
#define MM 5000
#define EE 320000
#define FD 128          // HEADS*OUT
#define KD 5000         // GEMM K == MM
#define K2 5120         // padded K (40 * 128)
#define NEG 0.2f
#define BK 128          // GEMM K-step (512B per H row per tile)
#define BUFB 65536      // one LDS buffer: A-f32(32KB) + B-bf16(32KB)
#define BOFF 32768      // B region offset inside a buffer
#define NKT 40          // total K-tiles (5120/128)
#define SPLITK 4
#define KTPS 10         // K-tiles per split (exact: 4*10=40)

typedef __attribute__((ext_vector_type(4))) float f32x4;
typedef __attribute__((ext_vector_type(8))) short short8;

__device__ __forceinline__ unsigned int f2bf(float x){
  unsigned int u = __float_as_uint(x);
  return (u + 0x7fffu + ((u >> 16) & 1u)) >> 16;   // RNE
}
__device__ __forceinline__ unsigned int cvtpk(float lo, float hi){
  unsigned int r;
  asm volatile("v_cvt_pk_bf16_f32 %0, %1, %2" : "=v"(r) : "v"(lo), "v"(hi));
  return r;
}
__device__ __forceinline__ void dma16(const void* g, void* l){
  __builtin_amdgcn_global_load_lds(
      (const __attribute__((address_space(1))) void*)g,
      (__attribute__((address_space(3))) void*)l, 16, 0, 0);
}

// ---- prep (fused k_el + k_feat16 + k_count): feat stream -> el + bf16 table;
// ---- first EE threads also histogram dst --------------------------------
__global__ __launch_bounds__(256) void k_prep(const float* __restrict__ feat,
                                              const float* __restrict__ attn_l,
                                              const int* __restrict__ dst,
                                              int* __restrict__ counts,
                                              float* __restrict__ el,
                                              unsigned int* __restrict__ fb){
  int t = threadIdx.x;
  int g = blockIdx.x*256 + t;
  if (g < EE) atomicAdd(&counts[dst[g]], 1);
  int node = blockIdx.x*4 + (t>>6);
  int l = t & 63;
  float2 f = ((const float2*)feat)[(size_t)node*64 + l];
  fb[(size_t)node*64 + l] = cvtpk(f.x, f.y);
  float p = f.x*attn_l[2*l] + f.y*attn_l[2*l+1];
  p += __shfl_xor(p,1); p += __shfl_xor(p,2); p += __shfl_xor(p,4); p += __shfl_xor(p,8);
  if ((l&15)==0) el[node*4 + (l>>4)] = p;
}

// ---------------- CSR scan --------------------------------------------------
__global__ __launch_bounds__(256) void k_scan(const int* __restrict__ counts,
                                              int* __restrict__ offsets){
  __shared__ int sc[256];
  int t = threadIdx.x;
  int loc[20];
  int sum = 0;
  #pragma unroll
  for (int j=0;j<20;j++){
    int idx = t*20 + j;
    int v = (idx < MM) ? counts[idx] : 0;
    loc[j] = sum; sum += v;
  }
  sc[t] = sum; __syncthreads();
  for (int s=1; s<256; s<<=1){
    int v = 0;
    if (t >= s) v = sc[t-s];
    __syncthreads();
    if (t >= s) sc[t] += v;
    __syncthreads();
  }
  int base = sc[t] - sum;   // exclusive over thread blocks
  #pragma unroll
  for (int j=0;j<20;j++){
    int idx = t*20 + j;
    if (idx < MM) offsets[idx] = base + loc[j];
  }
  if (t == 250) offsets[MM] = base;   // = total E
}

// ---- edge logits + DIRECT dst-sorted scatter (fused k_edge + k_scatter) ----
__global__ __launch_bounds__(256) void k_edge_sc(const float* __restrict__ edge_feat,
                                                 const float* __restrict__ attn_m,
                                                 const float* __restrict__ el,
                                                 const int* __restrict__ src,
                                                 const int* __restrict__ dst,
                                                 const int* __restrict__ offsets,
                                                 int* __restrict__ cursor,
                                                 float4* __restrict__ e4_s,
                                                 int* __restrict__ src_s){
  __shared__ float am[128];
  int t = threadIdx.x;
  if (t < 128) am[t] = attn_m[t];
  __syncthreads();
  int e = blockIdx.x*16 + (t>>4);
  int c = t & 15;
  float2 f = ((const float2*)edge_feat)[(size_t)e*16 + c];
  float p0 = f.x*am[0*32+2*c] + f.y*am[0*32+2*c+1];
  float p1 = f.x*am[1*32+2*c] + f.y*am[1*32+2*c+1];
  float p2 = f.x*am[2*32+2*c] + f.y*am[2*32+2*c+1];
  float p3 = f.x*am[3*32+2*c] + f.y*am[3*32+2*c+1];
  #pragma unroll
  for (int s=1; s<16; s<<=1){
    p0 += __shfl_xor(p0,s); p1 += __shfl_xor(p1,s);
    p2 += __shfl_xor(p2,s); p3 += __shfl_xor(p3,s);
  }
  if (c==0){
    float4 ev = ((const float4*)el)[src[e]];
    float4 r;
    float v;
    v = ev.x + p0; r.x = v > 0.f ? v : NEG*v;
    v = ev.y + p1; r.y = v > 0.f ? v : NEG*v;
    v = ev.z + p2; r.z = v > 0.f ? v : NEG*v;
    v = ev.w + p3; r.w = v > 0.f ? v : NEG*v;
    int d = dst[e];
    int pos = offsets[d] + atomicAdd(&cursor[d], 1);
    e4_s[pos] = r;
    src_s[pos] = src[e];
  }
}

// ------- per-dst softmax + aggregate; writes aggT[c][k] (bf16, K2-padded) ---
// (R13-proven: sorted streams, bf16 feat gather, const-shift exp, unroll x2)
__global__ __launch_bounds__(256) void k_agg(const float4* __restrict__ e4_s,
                                             const int* __restrict__ src_s,
                                             const unsigned int* __restrict__ fb,
                                             const int* __restrict__ offsets,
                                             unsigned short* __restrict__ aggT){
  int m = blockIdx.x;
  int t = threadIdx.x;
  // zero the K-pad region (k in [5000, 5120)) once per call
  if (m < (K2 - KD) && t < FD) aggT[(size_t)t*K2 + KD + m] = 0;
  int beg = offsets[m], end = offsets[m+1];
  int cnt = end - beg;
  if (cnt == 0){
    if (t < FD) aggT[(size_t)t*K2 + m] = 0;  // bf16 zero
    return;
  }
  __shared__ float accs[4][FD];
  __shared__ float dens[4][4];
  int w = t>>6, l = t&63, h = l>>4;
  float accx=0.f, accy=0.f, den=0.f;
  int i = w;
  #pragma unroll 1
  for (; i+4 < cnt; i += 8){           // unroll x2: two gathers in flight
    float4 ev0 = e4_s[beg+i];
    float4 ev1 = e4_s[beg+i+4];
    int s0 = src_s[beg+i];
    int s1 = src_s[beg+i+4];
    unsigned int v0 = fb[(size_t)s0*64 + l];
    unsigned int v1 = fb[(size_t)s1*64 + l];
    float eh0 = (h==0)?ev0.x:((h==1)?ev0.y:((h==2)?ev0.z:ev0.w));
    float eh1 = (h==0)?ev1.x:((h==1)?ev1.y:((h==2)?ev1.z:ev1.w));
    float p0 = __expf(eh0 - 32.0f);
    float p1 = __expf(eh1 - 32.0f);
    accx += p0*__uint_as_float(v0<<16) + p1*__uint_as_float(v1<<16);
    accy += p0*__uint_as_float(v0&0xffff0000u) + p1*__uint_as_float(v1&0xffff0000u);
    den  += p0 + p1;
  }
  if (i < cnt){
    float4 ev = e4_s[beg+i];
    int s0 = src_s[beg+i];
    unsigned int v = fb[(size_t)s0*64 + l];
    float eh = (h==0)?ev.x:((h==1)?ev.y:((h==2)?ev.z:ev.w));
    float p = __expf(eh - 32.0f);
    accx += p*__uint_as_float(v<<16);
    accy += p*__uint_as_float(v&0xffff0000u);
    den  += p;
  }
  accs[w][2*l]   = accx;
  accs[w][2*l+1] = accy;
  if ((l&15)==0) dens[w][h] = den;
  __syncthreads();
  if (t < FD){
    float s = accs[0][t]+accs[1][t]+accs[2][t]+accs[3][t];
    float dn = dens[0][t>>5]+dens[1][t>>5]+dens[2][t>>5]+dens[3][t>>5];
    aggT[(size_t)t*K2 + m] = (unsigned short)f2bf(s/dn);
  }
}

// ------- GEMM: out[N][128] += H[N][ksplit] * agg[ksplit][128] ---------------
// R12-proven core (BK=128, 512 thr / 8 waves, 2x64KB LDS, counted vmcnt(8)).
// SPLITK=4 (measured best; 8 regressed +19us, BM=128 variants regressed).
// Atomic split-K epilogue into out zeroed by hipMemsetAsync.
__global__ __launch_bounds__(512, 2) void k_gemm(const float* __restrict__ H,
                                                 const unsigned short* __restrict__ aggT,
                                                 float* __restrict__ out){
  __shared__ char lds[2*BUFB];
  int t = threadIdx.x;
  int row0 = blockIdx.x * 64;
  int kt0 = blockIdx.y * KTPS;

  int w8 = t>>6, l = t&63;
  const size_t AMAX = (size_t)NN*KD - 4;

  int wr = (w8>>2)*32, wc = (w8&3)*32;
  int rl = l&15, kg = l>>4;
  int arowA = (wr+rl)*512;
  int arowB = (wr+16+rl)*512;
  int bcol0 = BOFF + (wc+ 0+rl)*256;
  int bcol1 = BOFF + (wc+16+rl)*256;

  f32x4 acc00={0,0,0,0}, acc01={0,0,0,0};
  f32x4 acc10={0,0,0,0}, acc11={0,0,0,0};

#define STAGE(KT, BUF)                                                        \
  { size_t kb_ = (size_t)(KT)*BK;                                             \
    _Pragma("unroll")                                                         \
    for (int j=0;j<4;j++){   /* A: 2 rows per instr, 512B runs */             \
      int r_ = row0 + w8*8 + j*2 + (l>>5);                                    \
      if (r_ > NN-1) r_ = NN-1;                                               \
      size_t s_ = (size_t)r_*KD + (size_t)((l&31) ^ (r_&15))*4 + kb_;         \
      if (s_ > AMAX) s_ = AMAX;                                               \
      dma16(H + s_, (BUF) + (w8*8 + j*2)*512);                                \
    }                                                                         \
    _Pragma("unroll")                                                         \
    for (int j=0;j<4;j++){   /* B: 4 cols per instr, 256B runs */             \
      int c_ = w8*16 + j*4 + (l>>4);                                          \
      size_t s_ = (size_t)c_*K2 + (size_t)((l&15) ^ (c_&15))*8 + kb_;         \
      dma16(aggT + s_, (BUF) + BOFF + (w8*16 + j*4)*256);                     \
    }                                                                         \
  }

#define COMP_KK(R_, KK)                                                       \
  { int gA0 = (KK)*8 + kg*2;                                                  \
    int sA0 = ((gA0  ) ^ rl) << 4;                                            \
    int sA1 = ((gA0+1) ^ rl) << 4;                                            \
    f32x4 x0_ = *(const f32x4*)(R_ + arowA + sA0);                            \
    f32x4 x1_ = *(const f32x4*)(R_ + arowA + sA1);                            \
    f32x4 y0_ = *(const f32x4*)(R_ + arowB + sA0);                            \
    f32x4 y1_ = *(const f32x4*)(R_ + arowB + sA1);                            \
    int sB_ = (((KK)*4 + kg) ^ rl) << 4;                                      \
    short8 b0_ = *(const short8*)(R_ + bcol0 + sB_);                          \
    short8 b1_ = *(const short8*)(R_ + bcol1 + sB_);                          \
    uint4 ua_, ub_;                                                           \
    ua_.x = cvtpk(x0_[0],x0_[1]); ua_.y = cvtpk(x0_[2],x0_[3]);               \
    ua_.z = cvtpk(x1_[0],x1_[1]); ua_.w = cvtpk(x1_[2],x1_[3]);               \
    ub_.x = cvtpk(y0_[0],y0_[1]); ub_.y = cvtpk(y0_[2],y0_[3]);               \
    ub_.z = cvtpk(y1_[0],y1_[1]); ub_.w = cvtpk(y1_[2],y1_[3]);               \
    short8 a0_ = *(short8*)&ua_;                                              \
    short8 a1_ = *(short8*)&ub_;                                              \
    acc00 = __builtin_amdgcn_mfma_f32_16x16x32_bf16(a0_,b0_,acc00,0,0,0);     \
    acc01 = __builtin_amdgcn_mfma_f32_16x16x32_bf16(a0_,b1_,acc01,0,0,0);     \
    acc10 = __builtin_amdgcn_mfma_f32_16x16x32_bf16(a1_,b0_,acc10,0,0,0);     \
    acc11 = __builtin_amdgcn_mfma_f32_16x16x32_bf16(a1_,b1_,acc11,0,0,0);     \
  }

  STAGE(kt0,   lds)
  STAGE(kt0+1, lds + BUFB)

  int pr = 0;
  for (int tt = 0; tt < KTPS; ++tt){
    if (tt+1 < KTPS) { asm volatile("s_waitcnt vmcnt(8)" ::: "memory"); }
    else             { asm volatile("s_waitcnt vmcnt(0)" ::: "memory"); }
    __builtin_amdgcn_s_barrier();
    { const char* R_ = lds + pr*BUFB;
      COMP_KK(R_, 0)
      COMP_KK(R_, 1)
      COMP_KK(R_, 2)
      COMP_KK(R_, 3)
    }
    __builtin_amdgcn_s_barrier();
    __builtin_amdgcn_sched_barrier(0);
    if (tt+2 < KTPS) STAGE(kt0+tt+2, lds + pr*BUFB)
    pr ^= 1;
  }
#undef STAGE
#undef COMP_KK

  // epilogue: D row=(l>>4)*4+p, col=l&15 (m89-verified); split-K atomicAdd
#define STORE(ACC, FR, FN)                                                    \
  { _Pragma("unroll")                                                         \
    for (int q=0;q<4;q++){                                                    \
      int r = row0 + wr + (FR)*16 + kg*4 + q;                                 \
      if (r < NN) atomicAdd(&out[(size_t)r*FD + wc + (FN)*16 + rl], ACC[q]);  \
    } }
  STORE(acc00,0,0) STORE(acc01,0,1)
  STORE(acc10,1,0) STORE(acc11,1,1)
#undef STORE
}

extern "C" void kernel_launch(void* const* d_in, const int* in_sizes, int n_in,
                              void* d_out, int out_size, void* d_ws, size_t ws_size,
                              hipStream_t stream) {
  const float* feat      = (const float*)d_in[0];
  const float* edge_feat = (const float*)d_in[1];
  const float* H         = (const float*)d_in[2];
  const float* attn_l    = (const float*)d_in[3];
  const float* attn_m    = (const float*)d_in[4];
  const int*   src       = (const int*)d_in[5];
  const int*   dst       = (const int*)d_in[6];
  float* out = (float*)d_out;

  char* w = (char*)d_ws;
  // el ([0,320000)) and aggT ([0,1310720)) have disjoint lifetimes -> overlap
  float*          el       = (float*)(w + 0);                //  320000 B (dead after k_edge_sc)
  unsigned short* aggT     = (unsigned short*)(w + 0);       // 1310720 B (live from k_agg)
  int*            counts   = (int*)(w + 1310720);            //   20480 B
  int*            cursor   = (int*)(w + 1331200);            //   20480 B
  int*            offsets  = (int*)(w + 1351680);            //   20480 B
  int*            src_s    = (int*)(w + 1372160);            // 1280000 B
  float4*         e4_s     = (float4*)(w + 2652160);         // 5120000 B
  unsigned int*   fb       = (unsigned int*)(w + 7772160);   // 5120000 B (bf16 feat)
  // total ~12.9 MB

  hipMemsetAsync(counts, 0, 2*20480, stream);          // counts + cursor
  hipMemsetAsync(out, 0, (size_t)out_size*4, stream);  // split-K accumulator

  k_prep   <<<NN/4,   256, 0, stream>>>(feat, attn_l, dst, counts, el, fb);
  k_scan   <<<1,      256, 0, stream>>>(counts, offsets);
  k_edge_sc<<<EE/16,  256, 0, stream>>>(edge_feat, attn_m, el, src, dst,
                                        offsets, cursor, e4_s, src_s);
  k_agg    <<<MM,     256, 0, stream>>>(e4_s, src_s, fb, offsets, aggT);
  k_gemm   <<<dim3((NN+63)/64, SPLITK), 512, 0, stream>>>(H, aggT, out);
}